// Round 2
// baseline (258.816 us; speedup 1.0000x reference)
//
#include <hip/hip_runtime.h>
#include <stdint.h>
#include <stddef.h>

// MFMA fragment types (per guide: 8 bf16 in 4 VGPRs as short8)
typedef short bfrag __attribute__((ext_vector_type(8)));
typedef float f32x4 __attribute__((ext_vector_type(4)));

#define TBB 32            // batch tile per conv block
#define FSTRIDE 576       // feats row stride (560 + 16 zero pad), K-steps = 18
#define NSEQ 7

// per-seq geometry: L, Lp(pow2), shift=log2(Lp), P=Lp+9, bpt (samples per 16-row tile), mtpb, njobs
__constant__ int c_L[NSEQ]     = {12, 7, 8, 16, 6, 7, 18};
__constant__ int c_shift[NSEQ] = {4, 3, 3, 4, 3, 3, 5};
__constant__ int c_P[NSEQ]     = {25, 17, 17, 25, 17, 17, 41};
__constant__ int c_bpt[NSEQ]   = {1, 2, 2, 1, 2, 2, 1};
__constant__ int c_mtpb[NSEQ]  = {1, 1, 1, 1, 1, 1, 2};
__constant__ int c_njobs[NSEQ] = {32, 16, 16, 32, 16, 16, 32};
__constant__ int c_ks[5]       = {1, 3, 5, 7, 9};

static __device__ __forceinline__ unsigned short f2bf(float f) {
  unsigned int u = __float_as_uint(f);
  u += 0x7FFFu + ((u >> 16) & 1u);   // RNE
  return (unsigned short)(u >> 16);
}

// ---------------- prep: pack conv weights + lin1 weights into B-fragment layout ----------
// Wpack layout: [seq][nt(5)][step(7)][lane(64)] x 8 bf16 ; value = Wk[seq][f][c][tap]/5
//   k = step*32 + (lane>>4)*8 + j ; t = k/24 ; c = k%24 ; n = nt*16 + (lane&15) = (ksize nt, filter f)
// lin1pack: [nt(4)][step(18)][lane(64)] x 8 ; value = lin1_w[n][k], 0 for k>=560
struct PrepArgs {
  const float* Wk[5];
  const float* lin1_w;
  bfrag* Wpack;
  bfrag* lin1pack;
};

__global__ __launch_bounds__(256) void prep_kernel(PrepArgs a) {
  int tid = blockIdx.x * 256 + threadIdx.x;
  const int NW = NSEQ * 5 * 7 * 64;
  if (tid < NW) {
    int lane = tid & 63, rest = tid >> 6;
    int step = rest % 7, nt = (rest / 7) % 5, seq = rest / 35;
    int quad = lane >> 4, f = lane & 15;
    int ks = c_ks[nt], off = (9 - ks) >> 1;
    const float* W = a.Wk[nt];
    bfrag s;
#pragma unroll
    for (int j = 0; j < 8; ++j) {
      int k = step * 32 + quad * 8 + j;
      int t = k / 24, c = k % 24;
      int tap = t - off;
      float val = 0.f;
      if (c < 20 && tap >= 0 && tap < ks)
        val = W[((seq * 16 + f) * 20 + c) * ks + tap] * 0.2f;  // fold /5
      s[j] = (short)f2bf(val);
    }
    a.Wpack[tid] = s;
  } else if (tid < NW + 4 * 18 * 64) {
    int t2 = tid - NW;
    int lane = t2 & 63, rest = t2 >> 6;
    int step = rest % 18, nt = rest / 18;
    int quad = lane >> 4, col = lane & 15;
    int n = nt * 16 + col;
    bfrag s;
#pragma unroll
    for (int j = 0; j < 8; ++j) {
      int k = step * 32 + quad * 8 + j;
      float val = (k < 560) ? a.lin1_w[n * 560 + k] : 0.f;
      s[j] = (short)f2bf(val);
    }
    a.lin1pack[t2] = s;
  }
}

// ---------------- conv+relu+gmax: im2col MFMA GEMM, per-seq geometry ----------------
struct ConvArgs {
  const float* x[NSEQ];
  const bfrag* Wpack;
  unsigned short* feats;   // bf16 [B][FSTRIDE]
};

__global__ __launch_bounds__(256) void conv_kernel(ConvArgs a) {
  // x_lds[b_local][pos][c24] bf16 ; A addr (halfwords) = (b*P + l)*24 + k  (k = t*24+c)
  __shared__ unsigned short xl[TBB * 41 * 24];
  const int seq = blockIdx.y;
  const int L = c_L[seq], P = c_P[seq], shift = c_shift[seq];
  const int bpt = c_bpt[seq], mtpb = c_mtpb[seq], njobs = c_njobs[seq];
  const int b0 = blockIdx.x * TBB;
  const int tid = threadIdx.x;
  const float* xg = a.x[seq];

  // zero the staging region (covers c-pad, l-pad, halo)
  int nwords = TBB * P * 24 / 2;
  for (int i = tid; i < nwords; i += 256) ((unsigned int*)xl)[i] = 0u;
  __syncthreads();
  // stage x -> bf16 transposed [b][pos=xi+4][c]
  for (int r = tid; r < TBB * 20; r += 256) {
    int b = r / 20, c = r % 20;
    const float* src = xg + (size_t)((b0 + b) * 20 + c) * L;
    unsigned short* dst = xl + (b * P + 4) * 24 + c;
    for (int xi = 0; xi < L; ++xi) dst[xi * 24] = f2bf(src[xi]);
  }
  // zero feats pad columns once per batch-tile (seq 0 blocks own it)
  if (seq == 0) {
    for (int i = tid; i < TBB * 16; i += 256)
      a.feats[(size_t)(b0 + i / 16) * FSTRIDE + 560 + (i % 16)] = 0;
  }
  __syncthreads();

  const int wave = tid >> 6, lane = tid & 63, quad = lane >> 4, m = lane & 15;
  const int lmask = (1 << shift) - 1;

  for (int p = 0; p < 3; ++p) {                 // n-tile pairs: (0,1)(2,3)(4)
    const int na = p * 2;
    const int nb = (p == 2) ? 4 : na + 1;
    const bool two = (nb != na);
    bfrag Bf0[7], Bf1[7];
    const bfrag* wp0 = a.Wpack + (size_t)((seq * 5 + na) * 7) * 64 + lane;
    const bfrag* wp1 = a.Wpack + (size_t)((seq * 5 + nb) * 7) * 64 + lane;
#pragma unroll
    for (int s = 0; s < 7; ++s) { Bf0[s] = wp0[s * 64]; Bf1[s] = wp1[s * 64]; }

    for (int job = wave; job < njobs; job += 4) {
      float v0 = 0.f, v1 = 0.f;                 // relu folded in (init 0)
      for (int sub = 0; sub < mtpb; ++sub) {
        int r = (job * mtpb + sub) * 16 + m;    // global row in this block's M
        int bl = r >> shift, l = r & lmask;
        int rowbase = (bl * P + l) * 24 + quad * 8;
        bfrag Af[7];
#pragma unroll
        for (int s = 0; s < 7; ++s)
          Af[s] = *(const bfrag*)&xl[rowbase + s * 32];
        f32x4 acc0 = {0.f, 0.f, 0.f, 0.f}, acc1 = {0.f, 0.f, 0.f, 0.f};
#pragma unroll
        for (int s = 0; s < 7; ++s) {
          acc0 = __builtin_amdgcn_mfma_f32_16x16x32_bf16(Af[s], Bf0[s], acc0, 0, 0, 0);
          if (two)
            acc1 = __builtin_amdgcn_mfma_f32_16x16x32_bf16(Af[s], Bf1[s], acc1, 0, 0, 0);
        }
        // fold into running max, masking padding output rows (l >= L would be a
        // partial-window conv of real data — must NOT participate in global max)
#pragma unroll
        for (int r4 = 0; r4 < 4; ++r4) {
          int lrow = (sub * 16 + quad * 4 + r4) & lmask;
          bool ok = lrow < L;
          v0 = fmaxf(v0, ok ? acc0[r4] : 0.f);
          if (two) v1 = fmaxf(v1, ok ? acc1[r4] : 0.f);
        }
      }
      // cross-lane max over rows
      v0 = fmaxf(v0, __shfl_xor(v0, 16));
      if (two) v1 = fmaxf(v1, __shfl_xor(v1, 16));
      if (bpt == 1) {
        v0 = fmaxf(v0, __shfl_xor(v0, 32));
        if (two) v1 = fmaxf(v1, __shfl_xor(v1, 32));
        if (lane < 16) {
          size_t base = (size_t)(b0 + job) * FSTRIDE + seq * 80;
          a.feats[base + na * 16 + lane] = f2bf(v0);
          if (two) a.feats[base + nb * 16 + lane] = f2bf(v1);
        }
      } else {
        // rows 0-7 -> even sample (quads 0,1) ; rows 8-15 -> odd sample (quads 2,3)
        if ((lane & 16) == 0) {
          int b = b0 + job * 2 + (lane >> 5);
          size_t base = (size_t)b * FSTRIDE + seq * 80;
          a.feats[base + na * 16 + (lane & 15)] = f2bf(v0);
          if (two) a.feats[base + nb * 16 + (lane & 15)] = f2bf(v1);
        }
      }
    }
  }
}

// ---------------- MLP: feats[B,560] -> sigmoid(.@lin1^T+b1) -> @lin2^T+b2 ----------------
struct MlpArgs {
  const unsigned short* feats;
  const bfrag* lin1pack;
  const float* lin1_b;
  const float* lin2_w;
  const float* lin2_b;
  float* out;
};

__global__ __launch_bounds__(256) void mlp_kernel(MlpArgs a) {
  __shared__ float h[64 * 66];
  __shared__ float w2[64];
  const int tid = threadIdx.x;
  const int b0 = blockIdx.x * 64;
  if (tid < 64) w2[tid] = a.lin2_w[tid];
  const int wave = tid >> 6, lane = tid & 63, quad = lane >> 4, m = lane & 15;
  const int brow = wave * 16;
  const unsigned short* frow = a.feats + (size_t)(b0 + brow + m) * FSTRIDE;
  for (int nt = 0; nt < 4; ++nt) {
    f32x4 acc = {0.f, 0.f, 0.f, 0.f};
#pragma unroll
    for (int s = 0; s < 18; ++s) {
      bfrag af = *(const bfrag*)(frow + s * 32 + quad * 8);
      bfrag bf = a.lin1pack[(nt * 18 + s) * 64 + lane];
      acc = __builtin_amdgcn_mfma_f32_16x16x32_bf16(af, bf, acc, 0, 0, 0);
    }
    int n = nt * 16 + m;
    float bias = a.lin1_b[n];
#pragma unroll
    for (int r = 0; r < 4; ++r) {
      float pre = acc[r] + bias;
      h[(brow + quad * 4 + r) * 66 + n] = 1.f / (1.f + __expf(-pre));
    }
  }
  __syncthreads();
  int bl = tid >> 2, q = tid & 3;
  float s = 0.f;
  const float* hr = &h[bl * 66 + q * 16];
#pragma unroll
  for (int j = 0; j < 16; ++j) s += hr[j] * w2[q * 16 + j];
  s += __shfl_xor(s, 1);
  s += __shfl_xor(s, 2);
  if (q == 0) a.out[b0 + bl] = s + a.lin2_b[0];
}

// ---------------- launch ----------------
extern "C" void kernel_launch(void* const* d_in, const int* in_sizes, int n_in,
                              void* d_out, int out_size, void* d_ws, size_t ws_size,
                              hipStream_t stream) {
  (void)in_sizes; (void)n_in; (void)out_size; (void)ws_size;
  char* ws = (char*)d_ws;
  bfrag* Wpack = (bfrag*)(ws + 0);                 // 15680*16 = 250,880 B
  bfrag* lin1pack = (bfrag*)(ws + 262144);         // 4608*16  =  73,728 B
  unsigned short* feats = (unsigned short*)(ws + 393216);  // 16384*576*2 = 18.87 MB

  PrepArgs pa;
  for (int j = 0; j < 5; ++j) pa.Wk[j] = (const float*)d_in[7 + j];
  pa.lin1_w = (const float*)d_in[12];
  pa.Wpack = Wpack;
  pa.lin1pack = lin1pack;
  prep_kernel<<<80, 256, 0, stream>>>(pa);

  ConvArgs ca;
  for (int i = 0; i < NSEQ; ++i) ca.x[i] = (const float*)d_in[i];
  ca.Wpack = Wpack;
  ca.feats = feats;
  conv_kernel<<<dim3(16384 / TBB, NSEQ), 256, 0, stream>>>(ca);

  MlpArgs ma;
  ma.feats = feats;
  ma.lin1pack = lin1pack;
  ma.lin1_b = (const float*)d_in[13];
  ma.lin2_w = (const float*)d_in[14];
  ma.lin2_b = (const float*)d_in[15];
  ma.out = (float*)d_out;
  mlp_kernel<<<16384 / 64, 256, 0, stream>>>(ma);
}

// Round 4
// 205.148 us; speedup vs baseline: 1.2616x; 1.2616x over previous
//
#include <hip/hip_runtime.h>
#include <stdint.h>
#include <stddef.h>

typedef short bfrag __attribute__((ext_vector_type(8)));
typedef float f32x4 __attribute__((ext_vector_type(4)));

#define FSTRIDE 576       // feats row stride (560 + 16 zero pad), 18 K-steps for MLP
#define NSEQ 7

// per-seq: L, shift=log2(Lp), bpt (samples per 16-row tile)
__constant__ int c_L[NSEQ]     = {12, 7, 8, 16, 6, 7, 18};
__constant__ int c_shift[NSEQ] = {4, 3, 3, 4, 3, 3, 5};
__constant__ int c_bpt[NSEQ]   = {1, 2, 2, 1, 2, 2, 1};
__constant__ int c_ks[5]       = {1, 3, 5, 7, 9};

// per-ksize active MFMA K-steps (B is exactly zero outside): s in [lo, lo+n)
// k=1: taps k in [96,120) -> step 3 only. k=3: [72,144) -> 2..4. k=5: [48,168) -> 1..5.
// k=7: [24,192) -> 0..5. k=9: [0,216) -> 0..6.
#define SLO0 3
#define SLO1 2
#define SLO2 1
#define SLO3 0
#define SLO4 0
#define SN0 1
#define SN1 3
#define SN2 5
#define SN3 6
#define SN4 7

static __device__ __forceinline__ unsigned short f2bf(float f) {
  unsigned int u = __float_as_uint(f);
  u += 0x7FFFu + ((u >> 16) & 1u);   // RNE
  return (unsigned short)(u >> 16);
}

// ---------------- prep: pack conv weights + lin1 into B-fragment layout ----------
struct PrepArgs {
  const float* Wk[5];
  const float* lin1_w;
  bfrag* Wpack;
  bfrag* lin1pack;
};

__global__ __launch_bounds__(256) void prep_kernel(PrepArgs a) {
  int tid = blockIdx.x * 256 + threadIdx.x;
  const int NW = NSEQ * 5 * 7 * 64;
  if (tid < NW) {
    int lane = tid & 63, rest = tid >> 6;
    int step = rest % 7, nt = (rest / 7) % 5, seq = rest / 35;
    int quad = lane >> 4, f = lane & 15;
    int ks = c_ks[nt], off = (9 - ks) >> 1;
    const float* W = a.Wk[nt];
    bfrag s;
#pragma unroll
    for (int j = 0; j < 8; ++j) {
      int k = step * 32 + quad * 8 + j;
      int t = k / 24, c = k % 24;
      int tap = t - off;
      float val = 0.f;
      if (c < 20 && tap >= 0 && tap < ks)
        val = W[((seq * 16 + f) * 20 + c) * ks + tap] * 0.2f;  // fold /5
      s[j] = (short)f2bf(val);
    }
    a.Wpack[tid] = s;
  } else if (tid < NW + 4 * 18 * 64) {
    int t2 = tid - NW;
    int lane = t2 & 63, rest = t2 >> 6;
    int step = rest % 18, nt = rest / 18;
    int quad = lane >> 4, col = lane & 15;
    int n = nt * 16 + col;
    bfrag s;
#pragma unroll
    for (int j = 0; j < 8; ++j) {
      int k = step * 32 + quad * 8 + j;
      float val = (k < 560) ? a.lin1_w[n * 560 + k] : 0.f;
      s[j] = (short)f2bf(val);
    }
    a.lin1pack[t2] = s;
  }
}

// ---------------- conv+relu+gmax: im2col MFMA, templated geometry ----------------
struct ConvArgs {
  const float* x[NSEQ];
  const bfrag* Wpack;
  unsigned short* feats;   // bf16 [B][FSTRIDE]
};

// MT = 16-row tiles per job. One job ALWAYS covers whole samples:
//   MT=1: Lp<=16 (bpt=1 -> 1 sample/job ; bpt=2 -> 2 samples/job)
//   MT=2: Lp=32 (seq 6) -> 1 sample spans 2 tiles, max accumulated across subs
template <int TBBv, int Pv, int SEQ0, int MT>
__global__ __launch_bounds__(256, 3) void conv_kernel(ConvArgs a) {
  __shared__ unsigned short xl[TBBv * Pv * 24];   // [b][pos][c24] ; pos = xi + 4
  const int seq = SEQ0 + blockIdx.y;
  const int L = c_L[seq], shift = c_shift[seq], bpt = c_bpt[seq];
  const int njobs = ((TBBv << shift) >> 4) / MT;
  const int b0 = blockIdx.x * TBBv;
  const int tid = threadIdx.x;
  const float* xg = a.x[seq];

  // zero staging region (covers c-pad, l-pad, halo)
  const int nwords = TBBv * Pv * 24 / 2;
  for (int i = tid; i < nwords; i += 256) ((unsigned int*)xl)[i] = 0u;
  __syncthreads();
  // stage x -> bf16 [b][pos=xi+4][c]
  for (int r = tid; r < TBBv * 20; r += 256) {
    int b = r / 20, c = r % 20;
    const float* src = xg + (size_t)((b0 + b) * 20 + c) * L;
    unsigned short* dst = xl + (b * Pv + 4) * 24 + c;
    for (int xi = 0; xi < L; ++xi) dst[xi * 24] = f2bf(src[xi]);
  }
  // zero feats pad columns (seq-0 blocks cover all samples)
  if (SEQ0 == 0 && blockIdx.y == 0) {
    for (int i = tid; i < TBBv * 16; i += 256)
      a.feats[(size_t)(b0 + i / 16) * FSTRIDE + 560 + (i % 16)] = 0;
  }
  __syncthreads();

  const int wave = tid >> 6, lane = tid & 63, quad = lane >> 4, m = lane & 15;
  const int lmask = (1 << shift) - 1;

  // preload the 22 non-zero B fragments for this seq
  const bfrag* wp = a.Wpack + (size_t)(seq * 5 * 7) * 64 + lane;
  bfrag Bf[22];
  {
    int bi = 0;
#pragma unroll
    for (int i = 0; i < SN0; ++i) Bf[bi++] = wp[(0 * 7 + SLO0 + i) * 64];
#pragma unroll
    for (int i = 0; i < SN1; ++i) Bf[bi++] = wp[(1 * 7 + SLO1 + i) * 64];
#pragma unroll
    for (int i = 0; i < SN2; ++i) Bf[bi++] = wp[(2 * 7 + SLO2 + i) * 64];
#pragma unroll
    for (int i = 0; i < SN3; ++i) Bf[bi++] = wp[(3 * 7 + SLO3 + i) * 64];
#pragma unroll
    for (int i = 0; i < SN4; ++i) Bf[bi++] = wp[(4 * 7 + SLO4 + i) * 64];
  }
  // Bf base offsets per nt: {0, 1, 4, 9, 15}

  for (int job = wave; job < njobs; job += 4) {
    float v0 = 0.f, v1 = 0.f, v2 = 0.f, v3 = 0.f, v4 = 0.f;
#pragma unroll
    for (int sub = 0; sub < MT; ++sub) {
      int r = (job * MT + sub) * 16 + m;      // A row for this lane
      int bl = r >> shift, l = r & lmask;
      const unsigned short* arow = &xl[(bl * Pv + l) * 24 + quad * 8];
      f32x4 acc0 = {0.f, 0.f, 0.f, 0.f}, acc1 = acc0, acc2 = acc0, acc3 = acc0, acc4 = acc0;
#pragma unroll
      for (int s = 0; s < 7; ++s) {
        bfrag Af = *(const bfrag*)(arow + s * 32);
        if (s >= SLO0 && s < SLO0 + SN0)
          acc0 = __builtin_amdgcn_mfma_f32_16x16x32_bf16(Af, Bf[0 + s - SLO0], acc0, 0, 0, 0);
        if (s >= SLO1 && s < SLO1 + SN1)
          acc1 = __builtin_amdgcn_mfma_f32_16x16x32_bf16(Af, Bf[1 + s - SLO1], acc1, 0, 0, 0);
        if (s >= SLO2 && s < SLO2 + SN2)
          acc2 = __builtin_amdgcn_mfma_f32_16x16x32_bf16(Af, Bf[4 + s - SLO2], acc2, 0, 0, 0);
        if (s >= SLO3 && s < SLO3 + SN3)
          acc3 = __builtin_amdgcn_mfma_f32_16x16x32_bf16(Af, Bf[9 + s - SLO3], acc3, 0, 0, 0);
        acc4 = __builtin_amdgcn_mfma_f32_16x16x32_bf16(Af, Bf[15 + s], acc4, 0, 0, 0);
      }
      // relu+max fold; mask padding output rows (l >= L = partial-window garbage)
      // output row within sample: ((sub*16 + quad*4 + r4) & lmask)  [job*MT*16 & lmask == 0]
#pragma unroll
      for (int r4 = 0; r4 < 4; ++r4) {
        int lrow = ((sub << 4) + quad * 4 + r4) & lmask;
        bool ok = lrow < L;
        v0 = fmaxf(v0, ok ? acc0[r4] : 0.f);
        v1 = fmaxf(v1, ok ? acc1[r4] : 0.f);
        v2 = fmaxf(v2, ok ? acc2[r4] : 0.f);
        v3 = fmaxf(v3, ok ? acc3[r4] : 0.f);
        v4 = fmaxf(v4, ok ? acc4[r4] : 0.f);
      }
    }
    v0 = fmaxf(v0, __shfl_xor(v0, 16));
    v1 = fmaxf(v1, __shfl_xor(v1, 16));
    v2 = fmaxf(v2, __shfl_xor(v2, 16));
    v3 = fmaxf(v3, __shfl_xor(v3, 16));
    v4 = fmaxf(v4, __shfl_xor(v4, 16));
    if (bpt == 1) {
      v0 = fmaxf(v0, __shfl_xor(v0, 32));
      v1 = fmaxf(v1, __shfl_xor(v1, 32));
      v2 = fmaxf(v2, __shfl_xor(v2, 32));
      v3 = fmaxf(v3, __shfl_xor(v3, 32));
      v4 = fmaxf(v4, __shfl_xor(v4, 32));
      if (lane < 16) {
        unsigned short* p = a.feats + (size_t)(b0 + job) * FSTRIDE + seq * 80 + lane;
        p[0] = f2bf(v0); p[16] = f2bf(v1); p[32] = f2bf(v2); p[48] = f2bf(v3); p[64] = f2bf(v4);
      }
    } else {
      // out rows 0-7 (quads 0,1) -> even sample ; rows 8-15 (quads 2,3) -> odd
      if ((lane & 16) == 0) {
        int b = b0 + job * 2 + (lane >> 5);
        unsigned short* p = a.feats + (size_t)b * FSTRIDE + seq * 80 + (lane & 15);
        p[0] = f2bf(v0); p[16] = f2bf(v1); p[32] = f2bf(v2); p[48] = f2bf(v3); p[64] = f2bf(v4);
      }
    }
  }
}

// ---------------- MLP: feats[B,560] -> sigmoid(@lin1^T+b1) -> @lin2^T+b2 ----------------
struct MlpArgs {
  const unsigned short* feats;
  const bfrag* lin1pack;
  const float* lin1_b;
  const float* lin2_w;
  const float* lin2_b;
  float* out;
};

__global__ __launch_bounds__(256) void mlp_kernel(MlpArgs a) {
  __shared__ float h[16 * 68];
  __shared__ float w2[64];
  const int tid = threadIdx.x;
  const int b0 = blockIdx.x * 16;
  if (tid < 64) w2[tid] = a.lin2_w[tid];
  const int wave = tid >> 6, lane = tid & 63, quad = lane >> 4, m = lane & 15;
  const int nt = wave;                     // one n-tile per wave
  const unsigned short* frow = a.feats + (size_t)(b0 + m) * FSTRIDE;
  f32x4 acc = {0.f, 0.f, 0.f, 0.f};
#pragma unroll
  for (int s = 0; s < 18; ++s) {
    bfrag af = *(const bfrag*)(frow + s * 32 + quad * 8);
    bfrag bf = a.lin1pack[(nt * 18 + s) * 64 + lane];
    acc = __builtin_amdgcn_mfma_f32_16x16x32_bf16(af, bf, acc, 0, 0, 0);
  }
  int n = nt * 16 + m;
  float bias = a.lin1_b[n];
#pragma unroll
  for (int r = 0; r < 4; ++r) {
    float pre = acc[r] + bias;
    h[(quad * 4 + r) * 68 + n] = 1.f / (1.f + __expf(-pre));
  }
  __syncthreads();
  int bl = tid >> 4, q = tid & 15;
  const float* hr = &h[bl * 68 + q * 4];
  float s = hr[0] * w2[q * 4] + hr[1] * w2[q * 4 + 1] + hr[2] * w2[q * 4 + 2] + hr[3] * w2[q * 4 + 3];
  s += __shfl_xor(s, 1);
  s += __shfl_xor(s, 2);
  s += __shfl_xor(s, 4);
  s += __shfl_xor(s, 8);
  if (q == 0) a.out[b0 + bl] = s + a.lin2_b[0];
}

// ---------------- launch ----------------
extern "C" void kernel_launch(void* const* d_in, const int* in_sizes, int n_in,
                              void* d_out, int out_size, void* d_ws, size_t ws_size,
                              hipStream_t stream) {
  (void)in_sizes; (void)n_in; (void)out_size; (void)ws_size;
  char* ws = (char*)d_ws;
  bfrag* Wpack = (bfrag*)(ws + 0);                 // 15680*16 = 250,880 B
  bfrag* lin1pack = (bfrag*)(ws + 262144);         // 4608*16  =  73,728 B
  unsigned short* feats = (unsigned short*)(ws + 393216);  // 16384*576*2 = 18.87 MB

  PrepArgs pa;
  for (int j = 0; j < 5; ++j) pa.Wk[j] = (const float*)d_in[7 + j];
  pa.lin1_w = (const float*)d_in[12];
  pa.Wpack = Wpack;
  pa.lin1pack = lin1pack;
  prep_kernel<<<80, 256, 0, stream>>>(pa);

  ConvArgs ca;
  for (int i = 0; i < NSEQ; ++i) ca.x[i] = (const float*)d_in[i];
  ca.Wpack = Wpack;
  ca.feats = feats;
  // group 1: seqs 0-5, unified P=25 (Lp<=16), TBB=32, MT=1 -> 38.4 KB LDS
  conv_kernel<32, 25, 0, 1><<<dim3(16384 / 32, 6), 256, 0, stream>>>(ca);
  // group 2: seq 6 (Lp=32, P=41), TBB=16, MT=2 (1 sample = 2 tiles) -> 31.5 KB LDS
  conv_kernel<16, 41, 6, 2><<<dim3(16384 / 16, 1), 256, 0, stream>>>(ca);

  MlpArgs ma;
  ma.feats = feats;
  ma.lin1pack = lin1pack;
  ma.lin1_b = (const float*)d_in[13];
  ma.lin2_w = (const float*)d_in[14];
  ma.lin2_b = (const float*)d_in[15];
  ma.out = (float*)d_out;
  mlp_kernel<<<16384 / 16, 256, 0, stream>>>(ma);
}